// Round 2
// baseline (287.102 us; speedup 1.0000x reference)
//
#include <hip/hip_runtime.h>

#define NN 20000
#define EE 320000

typedef unsigned int  u32;
typedef unsigned short u16;

typedef _Float16 h8 __attribute__((ext_vector_type(8)));
typedef _Float16 h2 __attribute__((ext_vector_type(2)));
typedef float    f4 __attribute__((ext_vector_type(4)));

union U16 { uint4 u; h8 h; };

__device__ inline u32 phh(float a, float b){
  h2 v; v[0] = (_Float16)a; v[1] = (_Float16)b;
  return __builtin_bit_cast(u32, v);
}
__device__ inline u16 f2h_u(float a){
  _Float16 h = (_Float16)a;
  return __builtin_bit_cast(u16, h);
}
__device__ inline float2 up2(u32 u){
  h2 v = __builtin_bit_cast(h2, u);
  return make_float2((float)v[0], (float)v[1]);
}
__device__ inline h8 pack8(float4 a, float4 b){
  U16 t;
  t.u.x = phh(a.x, a.y);
  t.u.y = phh(a.z, a.w);
  t.u.z = phh(b.x, b.y);
  t.u.w = phh(b.z, b.w);
  return t.h;
}

// ---------------------------------------------------------------------------
// k0: pack all weights into MFMA fragment order, f16.
// Frag layout (16x16x32): lane holds M[k=(lane/16)*8+j][c=ct*16+lane%16].
// Same bytes serve as B-frag (M as [KxN] B) or A-frag (M^T as [16xK] A).
// ws (u16 units):
//   [0,65536)        W2pack: [d][ct(8)][ks(4)][lane(64)][j(8)]  (c 0-63=Wq, 64-127=Wk[d])
//   [65536,73728)    mw1pack: [ct(8)][ks(2)][lane][j]   (K=64)
//   [73728,90112)    mw2pack
//   [90112,106496)   mt1pack
//   [106496,122880)  mt2pack
// ---------------------------------------------------------------------------
__global__ void k0_pack(const float* __restrict__ Wq, const float* __restrict__ Wk,
                        const float* __restrict__ w1w, const float* __restrict__ w2w,
                        const float* __restrict__ w1t, const float* __restrict__ w2t,
                        u16* __restrict__ pack)
{
  const int tot = 65536 + 8192 + 16384*3;
  for (int o = blockIdx.x*blockDim.x + threadIdx.x; o < tot; o += gridDim.x*blockDim.x){
    float v;
    if (o < 65536){
      int d = o >> 14, r = o & 16383;
      int ct = r >> 11, ks = (r >> 9) & 3, lane = (r >> 3) & 63, j = r & 7;
      int k = ks*32 + (lane >> 4)*8 + j, c = ct*16 + (lane & 15);
      v = (c < 64) ? Wq[k*64 + c] : Wk[((d << 7) + k)*64 + (c - 64)];
    } else if (o < 73728){
      int r = o - 65536;
      int ct = r >> 10, ks = (r >> 9) & 1, lane = (r >> 3) & 63, j = r & 7;
      int k = ks*32 + (lane >> 4)*8 + j, c = ct*16 + (lane & 15);
      v = w1w[k*128 + c];
    } else {
      int r = o - 73728;
      int m = r >> 14; r &= 16383;
      int ct = r >> 11, ks = (r >> 9) & 3, lane = (r >> 3) & 63, j = r & 7;
      int k = ks*32 + (lane >> 4)*8 + j, c = ct*16 + (lane & 15);
      const float* M = (m == 0) ? w2w : (m == 1) ? w1t : w2t;
      v = M[k*128 + c];
    }
    pack[o] = f2h_u(v);
  }
}

// ---------------------------------------------------------------------------
// k1: per-d projection GEMM: [N x 128] @ [128 x 128] -> q||k per node, f16.
// (unchanged from round 1 — verified correct, ~small cost)
// ---------------------------------------------------------------------------
__global__ __launch_bounds__(256) void k1_proj(const float* __restrict__ X,
    const u16* __restrict__ wpack, u16* __restrict__ Q, u16* __restrict__ Kv)
{
  const int d = blockIdx.y;
  const int nBase = blockIdx.x * 64;
  const int wv = threadIdx.x >> 6;
  const int l  = threadIdx.x & 63;
  const int row16 = l & 15, g = l >> 4;
  int node_a = nBase + wv*16 + row16;
  int na = node_a < NN ? node_a : NN-1;          // clamp; stores are guarded
  const float* xrow = X + ((size_t)d*NN + na)*128;
  h8 a[4];
  #pragma unroll
  for (int ks = 0; ks < 4; ks++){
    float4 f0 = *(const float4*)(xrow + ks*32 + g*8);
    float4 f1 = *(const float4*)(xrow + ks*32 + g*8 + 4);
    a[ks] = pack8(f0, f1);
  }
  const uint4* wp4 = (const uint4*)wpack;
  #pragma unroll
  for (int ct = 0; ct < 8; ct++){
    f4 acc = {0.f, 0.f, 0.f, 0.f};
    #pragma unroll
    for (int ks = 0; ks < 4; ks++){
      U16 b; b.u = wp4[((d*8 + ct)*4 + ks)*64 + l];
      acc = __builtin_amdgcn_mfma_f32_16x16x32_f16(a[ks], b.h, acc, 0, 0, 0);
    }
    u16* dst = (ct < 4) ? Q : Kv;
    int cc = (ct & 3)*16 + row16;
    #pragma unroll
    for (int r = 0; r < 4; r++){
      int node = nBase + wv*16 + g*4 + r;        // D: col=lane&15, row=(lane>>4)*4+r
      if (node < NN) dst[(size_t)node*256 + d*64 + cc] = f2h_u(acc[r]);
    }
  }
}

// ---------------------------------------------------------------------------
// kA: gather + edge dot -> w_ij f16 [E][64] in ws. Pure latency machine:
// no LDS, low VGPR, 16 outstanding 16B loads/lane, coalesced 32B stores
// (4 lanes/edge cover the 128B w row contiguously).
// ---------------------------------------------------------------------------
__global__ __launch_bounds__(256) void kA_dot(
    const u16* __restrict__ Q, const u16* __restrict__ Kv,
    const int* __restrict__ eidx, u16* __restrict__ Wg)
{
  const int wv = threadIdx.x >> 6;
  const int l  = threadIdx.x & 63;
  const int eBase = (blockIdx.x*4 + wv)*16;
  const int er = l >> 2, p = l & 3;
  const int eg = eBase + er;
  const int nj = eidx[eg];        // edge_index[0] = n_j (sender, uses ek)
  const int ni = eidx[EE + eg];   // edge_index[1] = n_i (receiver, uses eq)
  const u16* qb = Q  + (size_t)ni*256 + p*16;
  const u16* kb = Kv + (size_t)nj*256 + p*16;
  float acc16[16];
  #pragma unroll
  for (int j = 0; j < 16; j++) acc16[j] = 0.f;
  #pragma unroll
  for (int dd = 0; dd < 4; dd++){
    uint4 qa = *(const uint4*)(qb + dd*64);
    uint4 qc = *(const uint4*)(qb + dd*64 + 8);
    uint4 ka = *(const uint4*)(kb + dd*64);
    uint4 kc = *(const uint4*)(kb + dd*64 + 8);
    u32 qs[8] = {qa.x,qa.y,qa.z,qa.w,qc.x,qc.y,qc.z,qc.w};
    u32 ks_[8] = {ka.x,ka.y,ka.z,ka.w,kc.x,kc.y,kc.z,kc.w};
    #pragma unroll
    for (int j = 0; j < 8; j++){
      float2 qf = up2(qs[j]), kf = up2(ks_[j]);
      acc16[2*j]   += qf.x * kf.x;
      acc16[2*j+1] += qf.y * kf.y;
    }
  }
  uint4 wlo, whi;
  wlo.x = phh(acc16[0],acc16[1]);   wlo.y = phh(acc16[2],acc16[3]);
  wlo.z = phh(acc16[4],acc16[5]);   wlo.w = phh(acc16[6],acc16[7]);
  whi.x = phh(acc16[8],acc16[9]);   whi.y = phh(acc16[10],acc16[11]);
  whi.z = phh(acc16[12],acc16[13]); whi.w = phh(acc16[14],acc16[15]);
  uint4* dst = (uint4*)(Wg + (size_t)eg*64 + p*16);
  dst[0] = wlo;
  dst[1] = whi;
}

// ---------------------------------------------------------------------------
// k2_mlp: streaming 4-layer MFMA kernel, transposed orientation.
// mfma(A = packed-weight frag (W^T), B = activation frag) -> D[feat][edge]:
//   - h tiles: b64 LDS writes (4 consecutive feats per lane), b128 reads,
//     16B-granule XOR swizzle (conflict-free both directions)
//   - epilogue: float4 stores, fully coalesced
// Per-wave 16 edges, zero barriers (LDS sliced per wave).
// ---------------------------------------------------------------------------
__global__ __launch_bounds__(256) void k2_mlp(
    const u16* __restrict__ Wg, const float* __restrict__ T,
    const uint4* __restrict__ mw1p, const uint4* __restrict__ mw2p,
    const uint4* __restrict__ mt1p, const uint4* __restrict__ mt2p,
    const float* __restrict__ b1w, const float* __restrict__ b2w,
    const float* __restrict__ b1t, const float* __restrict__ b2t,
    float* __restrict__ out)
{
  __shared__ alignas(16) u16 ht[4][16*128];
  __shared__ alignas(16) u16 hw[4][16*128];
  const int wv = threadIdx.x >> 6;
  const int l  = threadIdx.x & 63;
  const int e16 = l & 15, g = l >> 4;
  const int eBase = (blockIdx.x*4 + wv)*16;
  const int swz = (e16 & 7) << 3;          // elem-unit XOR == 16B-granule byte XOR

  // ---- input B-frags (global, coalesced) ----
  U16 wf[2];
  {
    const uint4* wrow = (const uint4*)(Wg + (size_t)(eBase + e16)*64);
    wf[0].u = wrow[g];        // elems ks*32+g*8 .. +7, ks=0
    wf[1].u = wrow[4 + g];    // ks=1
  }
  h8 tf[4];
  {
    const float* trow = T + (size_t)(eBase + e16)*128;
    #pragma unroll
    for (int ks = 0; ks < 4; ks++){
      float4 f0 = *(const float4*)(trow + ks*32 + g*8);
      float4 f1 = *(const float4*)(trow + ks*32 + g*8 + 4);
      tf[ks] = pack8(f0, f1);
    }
  }

  // ---- t-MLP layer 1 -> ht ----
  #pragma unroll
  for (int ct = 0; ct < 8; ct++){
    f4 acc = {0.f,0.f,0.f,0.f};
    #pragma unroll
    for (int ks = 0; ks < 4; ks++){
      U16 a; a.u = mt1p[(ct*4 + ks)*64 + l];
      acc = __builtin_amdgcn_mfma_f32_16x16x32_f16(a.h, tf[ks], acc, 0, 0, 0);
    }
    float4 bb = *(const float4*)&b1t[ct*16 + g*4];
    u32 lo = phh(fmaxf(acc[0]+bb.x, 0.f), fmaxf(acc[1]+bb.y, 0.f));
    u32 hi = phh(fmaxf(acc[2]+bb.z, 0.f), fmaxf(acc[3]+bb.w, 0.f));
    uint2 val; val.x = lo; val.y = hi;
    *(uint2*)&ht[wv][e16*128 + ((ct*16 + g*4) ^ swz)] = val;
  }

  // ---- w-MLP layer 1 -> hw ----
  #pragma unroll
  for (int ct = 0; ct < 8; ct++){
    f4 acc = {0.f,0.f,0.f,0.f};
    #pragma unroll
    for (int ks = 0; ks < 2; ks++){
      U16 a; a.u = mw1p[(ct*2 + ks)*64 + l];
      acc = __builtin_amdgcn_mfma_f32_16x16x32_f16(a.h, wf[ks].h, acc, 0, 0, 0);
    }
    float4 bb = *(const float4*)&b1w[ct*16 + g*4];
    u32 lo = phh(fmaxf(acc[0]+bb.x, 0.f), fmaxf(acc[1]+bb.y, 0.f));
    u32 hi = phh(fmaxf(acc[2]+bb.z, 0.f), fmaxf(acc[3]+bb.w, 0.f));
    uint2 val; val.x = lo; val.y = hi;
    *(uint2*)&hw[wv][e16*128 + ((ct*16 + g*4) ^ swz)] = val;
  }

  // ---- t-MLP layer 2 -> accT ----
  U16 hf[4];
  #pragma unroll
  for (int ks = 0; ks < 4; ks++)
    hf[ks].u = *(const uint4*)&ht[wv][e16*128 + ((ks*32 + g*8) ^ swz)];
  f4 accT[8];
  #pragma unroll
  for (int ct = 0; ct < 8; ct++){
    f4 acc = {0.f,0.f,0.f,0.f};
    #pragma unroll
    for (int ks = 0; ks < 4; ks++){
      U16 a; a.u = mt2p[(ct*4 + ks)*64 + l];
      acc = __builtin_amdgcn_mfma_f32_16x16x32_f16(a.h, hf[ks].h, acc, 0, 0, 0);
    }
    accT[ct] = acc;
  }

  // ---- w-MLP layer 2 + fused epilogue ----
  U16 hg[4];
  #pragma unroll
  for (int ks = 0; ks < 4; ks++)
    hg[ks].u = *(const uint4*)&hw[wv][e16*128 + ((ks*32 + g*8) ^ swz)];
  #pragma unroll
  for (int ct = 0; ct < 8; ct++){
    f4 acc = {0.f,0.f,0.f,0.f};
    #pragma unroll
    for (int ks = 0; ks < 4; ks++){
      U16 a; a.u = mw2p[(ct*4 + ks)*64 + l];
      acc = __builtin_amdgcn_mfma_f32_16x16x32_f16(a.h, hg[ks].h, acc, 0, 0, 0);
    }
    float4 bw = *(const float4*)&b2w[ct*16 + g*4];
    float4 bt = *(const float4*)&b2t[ct*16 + g*4];
    float4 o;
    o.x = (acc[0] + bw.x) * (accT[ct][0] + bt.x);
    o.y = (acc[1] + bw.y) * (accT[ct][1] + bt.y);
    o.z = (acc[2] + bw.z) * (accT[ct][2] + bt.z);
    o.w = (acc[3] + bw.w) * (accT[ct][3] + bt.w);
    *(float4*)&out[(size_t)(eBase + e16)*128 + ct*16 + g*4] = o;
  }
}

extern "C" void kernel_launch(void* const* d_in, const int* in_sizes, int n_in,
                              void* d_out, int out_size, void* d_ws, size_t ws_size,
                              hipStream_t stream) {
  const float* X   = (const float*)d_in[0];
  const float* T   = (const float*)d_in[1];
  const int*   EI  = (const int*)  d_in[2];
  const float* Wq  = (const float*)d_in[3];
  const float* Wk  = (const float*)d_in[4];
  const float* w1w = (const float*)d_in[5];
  const float* b1w = (const float*)d_in[6];
  const float* w2w = (const float*)d_in[7];
  const float* b2w = (const float*)d_in[8];
  const float* w1t = (const float*)d_in[9];
  const float* b1t = (const float*)d_in[10];
  const float* w2t = (const float*)d_in[11];
  const float* b2t = (const float*)d_in[12];
  float* out = (float*)d_out;

  u16* ws   = (u16*)d_ws;
  u16* pack = ws;                           // 240 KB packed weights
  u16* Q    = ws + 122880;                  // [N][256] f16 (10.24 MB)
  u16* Kv   = Q + (size_t)NN*256;           // [N][256] f16 (10.24 MB)
  u16* Wg   = Kv + (size_t)NN*256;          // [E][64] f16  (40.96 MB)

  k0_pack<<<64, 256, 0, stream>>>(Wq, Wk, w1w, w2w, w1t, w2t, pack);
  k1_proj<<<dim3((NN + 63)/64, 4), 256, 0, stream>>>(X, pack, Q, Kv);
  kA_dot<<<EE/64, 256, 0, stream>>>(Q, Kv, EI, Wg);
  k2_mlp<<<EE/64, 256, 0, stream>>>(Wg, T,
      (const uint4*)(ws + 65536), (const uint4*)(ws + 73728),
      (const uint4*)(ws + 90112), (const uint4*)(ws + 106496),
      b1w, b2w, b1t, b2t, out);
}

// Round 4
// 197.141 us; speedup vs baseline: 1.4563x; 1.4563x over previous
//
#include <hip/hip_runtime.h>

#define NN 20000
#define EE 320000

typedef unsigned int  u32;
typedef unsigned short u16;

typedef _Float16 h8 __attribute__((ext_vector_type(8)));
typedef _Float16 h2 __attribute__((ext_vector_type(2)));
typedef float    f4 __attribute__((ext_vector_type(4)));

union U16 { uint4 u; h8 h; };

__device__ inline u32 phh(float a, float b){
  h2 v; v[0] = (_Float16)a; v[1] = (_Float16)b;
  return __builtin_bit_cast(u32, v);
}
__device__ inline u16 f2h_u(float a){
  _Float16 h = (_Float16)a;
  return __builtin_bit_cast(u16, h);
}
__device__ inline float2 up2(u32 u){
  h2 v = __builtin_bit_cast(h2, u);
  return make_float2((float)v[0], (float)v[1]);
}
__device__ inline h8 pack8(float4 a, float4 b){
  U16 t;
  t.u.x = phh(a.x, a.y);
  t.u.y = phh(a.z, a.w);
  t.u.z = phh(b.x, b.y);
  t.u.w = phh(b.z, b.w);
  return t.h;
}

// ---------------------------------------------------------------------------
// k0: pack all weights into MFMA fragment order, f16.
// Frag layout (16x16x32): lane holds M[k=(lane/16)*8+j][c=ct*16+lane%16].
// ws (u16 units):
//   [0,65536)        W2pack: [d][ct(8)][ks(4)][lane(64)][j(8)]  (c 0-63=Wq, 64-127=Wk[d])
//   [65536,73728)    mw1pack: [ct(8)][ks(2)][lane][j]   (K=64)
//   [73728,90112)    mw2pack
//   [90112,106496)   mt1pack
//   [106496,122880)  mt2pack
// ---------------------------------------------------------------------------
__global__ void k0_pack(const float* __restrict__ Wq, const float* __restrict__ Wk,
                        const float* __restrict__ w1w, const float* __restrict__ w2w,
                        const float* __restrict__ w1t, const float* __restrict__ w2t,
                        u16* __restrict__ pack)
{
  const int tot = 65536 + 8192 + 16384*3;
  for (int o = blockIdx.x*blockDim.x + threadIdx.x; o < tot; o += gridDim.x*blockDim.x){
    float v;
    if (o < 65536){
      int d = o >> 14, r = o & 16383;
      int ct = r >> 11, ks = (r >> 9) & 3, lane = (r >> 3) & 63, j = r & 7;
      int k = ks*32 + (lane >> 4)*8 + j, c = ct*16 + (lane & 15);
      v = (c < 64) ? Wq[k*64 + c] : Wk[((d << 7) + k)*64 + (c - 64)];
    } else if (o < 73728){
      int r = o - 65536;
      int ct = r >> 10, ks = (r >> 9) & 1, lane = (r >> 3) & 63, j = r & 7;
      int k = ks*32 + (lane >> 4)*8 + j, c = ct*16 + (lane & 15);
      v = w1w[k*128 + c];
    } else {
      int r = o - 73728;
      int m = r >> 14; r &= 16383;
      int ct = r >> 11, ks = (r >> 9) & 3, lane = (r >> 3) & 63, j = r & 7;
      int k = ks*32 + (lane >> 4)*8 + j, c = ct*16 + (lane & 15);
      const float* M = (m == 0) ? w2w : (m == 1) ? w1t : w2t;
      v = M[k*128 + c];
    }
    pack[o] = f2h_u(v);
  }
}

// ---------------------------------------------------------------------------
// k1: per-d projection GEMM: [N x 128] @ [128 x 128] -> q||k per node, f16.
// ---------------------------------------------------------------------------
__global__ __launch_bounds__(256) void k1_proj(const float* __restrict__ X,
    const u16* __restrict__ wpack, u16* __restrict__ Q, u16* __restrict__ Kv)
{
  const int d = blockIdx.y;
  const int nBase = blockIdx.x * 64;
  const int wv = threadIdx.x >> 6;
  const int l  = threadIdx.x & 63;
  const int row16 = l & 15, g = l >> 4;
  int node_a = nBase + wv*16 + row16;
  int na = node_a < NN ? node_a : NN-1;          // clamp; stores are guarded
  const float* xrow = X + ((size_t)d*NN + na)*128;
  h8 a[4];
  #pragma unroll
  for (int ks = 0; ks < 4; ks++){
    float4 f0 = *(const float4*)(xrow + ks*32 + g*8);
    float4 f1 = *(const float4*)(xrow + ks*32 + g*8 + 4);
    a[ks] = pack8(f0, f1);
  }
  const uint4* wp4 = (const uint4*)wpack;
  #pragma unroll
  for (int ct = 0; ct < 8; ct++){
    f4 acc = {0.f, 0.f, 0.f, 0.f};
    #pragma unroll
    for (int ks = 0; ks < 4; ks++){
      U16 b; b.u = wp4[((d*8 + ct)*4 + ks)*64 + l];
      acc = __builtin_amdgcn_mfma_f32_16x16x32_f16(a[ks], b.h, acc, 0, 0, 0);
    }
    u16* dst = (ct < 4) ? Q : Kv;
    int cc = (ct & 3)*16 + row16;
    #pragma unroll
    for (int r = 0; r < 4; r++){
      int node = nBase + wv*16 + g*4 + r;        // D: col=lane&15, row=(lane>>4)*4+r
      if (node < NN) dst[(size_t)node*256 + d*64 + cc] = f2h_u(acc[r]);
    }
  }
}

// ---------------------------------------------------------------------------
// kA: gather + edge dot -> w_ij f16 [E][64] in ws.
// ---------------------------------------------------------------------------
__global__ __launch_bounds__(256) void kA_dot(
    const u16* __restrict__ Q, const u16* __restrict__ Kv,
    const int* __restrict__ eidx, u16* __restrict__ Wg)
{
  const int wv = threadIdx.x >> 6;
  const int l  = threadIdx.x & 63;
  const int eBase = (blockIdx.x*4 + wv)*16;
  const int er = l >> 2, p = l & 3;
  const int eg = eBase + er;
  const int nj = eidx[eg];        // edge_index[0] = n_j (sender, uses ek)
  const int ni = eidx[EE + eg];   // edge_index[1] = n_i (receiver, uses eq)
  const u16* qb = Q  + (size_t)ni*256 + p*16;
  const u16* kb = Kv + (size_t)nj*256 + p*16;
  float acc16[16];
  #pragma unroll
  for (int j = 0; j < 16; j++) acc16[j] = 0.f;
  #pragma unroll
  for (int dd = 0; dd < 4; dd++){
    uint4 qa = *(const uint4*)(qb + dd*64);
    uint4 qc = *(const uint4*)(qb + dd*64 + 8);
    uint4 ka = *(const uint4*)(kb + dd*64);
    uint4 kc = *(const uint4*)(kb + dd*64 + 8);
    u32 qs[8] = {qa.x,qa.y,qa.z,qa.w,qc.x,qc.y,qc.z,qc.w};
    u32 ks_[8] = {ka.x,ka.y,ka.z,ka.w,kc.x,kc.y,kc.z,kc.w};
    #pragma unroll
    for (int j = 0; j < 8; j++){
      float2 qf = up2(qs[j]), kf = up2(ks_[j]);
      acc16[2*j]   += qf.x * kf.x;
      acc16[2*j+1] += qf.y * kf.y;
    }
  }
  uint4 wlo, whi;
  wlo.x = phh(acc16[0],acc16[1]);   wlo.y = phh(acc16[2],acc16[3]);
  wlo.z = phh(acc16[4],acc16[5]);   wlo.w = phh(acc16[6],acc16[7]);
  whi.x = phh(acc16[8],acc16[9]);   whi.y = phh(acc16[10],acc16[11]);
  whi.z = phh(acc16[12],acc16[13]); whi.w = phh(acc16[14],acc16[15]);
  uint4* dst = (uint4*)(Wg + (size_t)eg*64 + p*16);
  dst[0] = wlo;
  dst[1] = whi;
}

// ---------------------------------------------------------------------------
// k2_mlp v2: 2 edge-tiles (32 edges) per wave, t-chain and w-chain interleaved.
// Phase 1: both L1 layers (independent MFMA chains, weight frag reused 2x).
// Phase 2: both L2 layers + fused epilogue (accs consumed immediately).
// h tiles in per-wave LDS (16KB/wave), XOR-swizzled; zero barriers.
// Block = 128 threads = 2 waves = 64 edges  ->  grid = EE/64.
// ---------------------------------------------------------------------------
__global__ __launch_bounds__(128, 3) void k2_mlp(
    const u16* __restrict__ Wg, const float* __restrict__ T,
    const uint4* __restrict__ mw1p, const uint4* __restrict__ mw2p,
    const uint4* __restrict__ mt1p, const uint4* __restrict__ mt2p,
    const float* __restrict__ b1w, const float* __restrict__ b2w,
    const float* __restrict__ b1t, const float* __restrict__ b2t,
    float* __restrict__ out)
{
  __shared__ alignas(16) u16 ht[2][2][16*128];   // [wave][tile][edge16*128]
  __shared__ alignas(16) u16 hw[2][2][16*128];
  const int wv = threadIdx.x >> 6;
  const int l  = threadIdx.x & 63;
  const int e16 = l & 15, g = l >> 4;
  const int eBase = (blockIdx.x*2 + wv)*32;
  const int swz = (e16 & 7) << 3;                // elem-unit XOR == 16B granule

  // ---- input B-frags: w (2 tiles x 2 frags), t (2 tiles x 4 frags) ----
  U16 wf[2][2];
  h8  tf[2][4];
  #pragma unroll
  for (int tile = 0; tile < 2; tile++){
    const uint4* wrow = (const uint4*)(Wg + (size_t)(eBase + tile*16 + e16)*64);
    wf[tile][0].u = wrow[g];
    wf[tile][1].u = wrow[4 + g];
    const float* trow = T + (size_t)(eBase + tile*16 + e16)*128;
    #pragma unroll
    for (int ks = 0; ks < 4; ks++){
      float4 f0 = *(const float4*)(trow + ks*32 + g*8);
      float4 f1 = *(const float4*)(trow + ks*32 + g*8 + 4);
      tf[tile][ks] = pack8(f0, f1);
    }
  }

  // ---- phase 1: t-L1 and w-L1 interleaved ----
  #pragma unroll
  for (int ct = 0; ct < 8; ct++){
    U16 at_[4], aw_[2];
    #pragma unroll
    for (int ks = 0; ks < 4; ks++) at_[ks].u = mt1p[(ct*4 + ks)*64 + l];
    #pragma unroll
    for (int ks = 0; ks < 2; ks++) aw_[ks].u = mw1p[(ct*2 + ks)*64 + l];
    f4 A0 = {0.f,0.f,0.f,0.f}, A1 = A0, B0 = A0, B1 = A0;
    #pragma unroll
    for (int ks = 0; ks < 4; ks++){
      A0 = __builtin_amdgcn_mfma_f32_16x16x32_f16(at_[ks].h, tf[0][ks], A0, 0, 0, 0);
      A1 = __builtin_amdgcn_mfma_f32_16x16x32_f16(at_[ks].h, tf[1][ks], A1, 0, 0, 0);
    }
    #pragma unroll
    for (int ks = 0; ks < 2; ks++){
      B0 = __builtin_amdgcn_mfma_f32_16x16x32_f16(aw_[ks].h, wf[0][ks].h, B0, 0, 0, 0);
      B1 = __builtin_amdgcn_mfma_f32_16x16x32_f16(aw_[ks].h, wf[1][ks].h, B1, 0, 0, 0);
    }
    float4 bt = *(const float4*)&b1t[ct*16 + g*4];
    float4 bw = *(const float4*)&b1w[ct*16 + g*4];
    const int hidx = e16*128 + ((ct*16 + g*4) ^ swz);
    uint2 v;
    v.x = phh(fmaxf(A0[0]+bt.x,0.f), fmaxf(A0[1]+bt.y,0.f));
    v.y = phh(fmaxf(A0[2]+bt.z,0.f), fmaxf(A0[3]+bt.w,0.f));
    *(uint2*)&ht[wv][0][hidx] = v;
    v.x = phh(fmaxf(A1[0]+bt.x,0.f), fmaxf(A1[1]+bt.y,0.f));
    v.y = phh(fmaxf(A1[2]+bt.z,0.f), fmaxf(A1[3]+bt.w,0.f));
    *(uint2*)&ht[wv][1][hidx] = v;
    v.x = phh(fmaxf(B0[0]+bw.x,0.f), fmaxf(B0[1]+bw.y,0.f));
    v.y = phh(fmaxf(B0[2]+bw.z,0.f), fmaxf(B0[3]+bw.w,0.f));
    *(uint2*)&hw[wv][0][hidx] = v;
    v.x = phh(fmaxf(B1[0]+bw.x,0.f), fmaxf(B1[1]+bw.y,0.f));
    v.y = phh(fmaxf(B1[2]+bw.z,0.f), fmaxf(B1[3]+bw.w,0.f));
    *(uint2*)&hw[wv][1][hidx] = v;
  }

  // ---- hidden B-frags (same-wave DS ops are in-order: no barrier) ----
  U16 hT[2][4], hW[2][4];
  #pragma unroll
  for (int tile = 0; tile < 2; tile++){
    #pragma unroll
    for (int ks = 0; ks < 4; ks++){
      const int ridx = e16*128 + ((ks*32 + g*8) ^ swz);
      hT[tile][ks].u = *(const uint4*)&ht[wv][tile][ridx];
      hW[tile][ks].u = *(const uint4*)&hw[wv][tile][ridx];
    }
  }

  // ---- phase 2: t-L2 and w-L2 interleaved + fused epilogue ----
  #pragma unroll
  for (int ct = 0; ct < 8; ct++){
    U16 a2t[4], a2w[4];
    #pragma unroll
    for (int ks = 0; ks < 4; ks++){
      a2t[ks].u = mt2p[(ct*4 + ks)*64 + l];
      a2w[ks].u = mw2p[(ct*4 + ks)*64 + l];
    }
    float4 ct2 = *(const float4*)&b2t[ct*16 + g*4];
    float4 cw2 = *(const float4*)&b2w[ct*16 + g*4];
    #pragma unroll
    for (int tile = 0; tile < 2; tile++){
      f4 X = {0.f,0.f,0.f,0.f}, Y = X;
      #pragma unroll
      for (int ks = 0; ks < 4; ks++){
        X = __builtin_amdgcn_mfma_f32_16x16x32_f16(a2t[ks].h, hT[tile][ks].h, X, 0, 0, 0);
        Y = __builtin_amdgcn_mfma_f32_16x16x32_f16(a2w[ks].h, hW[tile][ks].h, Y, 0, 0, 0);
      }
      float4 o;
      o.x = (Y[0] + cw2.x) * (X[0] + ct2.x);
      o.y = (Y[1] + cw2.y) * (X[1] + ct2.y);
      o.z = (Y[2] + cw2.z) * (X[2] + ct2.z);
      o.w = (Y[3] + cw2.w) * (X[3] + ct2.w);
      *(float4*)&out[(size_t)(eBase + tile*16 + e16)*128 + ct*16 + g*4] = o;
    }
  }
}

extern "C" void kernel_launch(void* const* d_in, const int* in_sizes, int n_in,
                              void* d_out, int out_size, void* d_ws, size_t ws_size,
                              hipStream_t stream) {
  const float* X   = (const float*)d_in[0];
  const float* T   = (const float*)d_in[1];
  const int*   EI  = (const int*)  d_in[2];
  const float* Wq  = (const float*)d_in[3];
  const float* Wk  = (const float*)d_in[4];
  const float* w1w = (const float*)d_in[5];
  const float* b1w = (const float*)d_in[6];
  const float* w2w = (const float*)d_in[7];
  const float* b2w = (const float*)d_in[8];
  const float* w1t = (const float*)d_in[9];
  const float* b1t = (const float*)d_in[10];
  const float* w2t = (const float*)d_in[11];
  const float* b2t = (const float*)d_in[12];
  float* out = (float*)d_out;

  u16* ws   = (u16*)d_ws;
  u16* pack = ws;                           // 240 KB packed weights
  u16* Q    = ws + 122880;                  // [N][256] f16 (10.24 MB)
  u16* Kv   = Q + (size_t)NN*256;           // [N][256] f16 (10.24 MB)
  u16* Wg   = Kv + (size_t)NN*256;          // [E][64] f16  (40.96 MB)

  k0_pack<<<64, 256, 0, stream>>>(Wq, Wk, w1w, w2w, w1t, w2t, pack);
  k1_proj<<<dim3((NN + 63)/64, 4), 256, 0, stream>>>(X, pack, Q, Kv);
  kA_dot<<<EE/64, 256, 0, stream>>>(Q, Kv, EI, Wg);
  k2_mlp<<<EE/64, 128, 0, stream>>>(Wg, T,   // 64 edges per block (2 waves x 32)
      (const uint4*)(ws + 65536), (const uint4*)(ws + 73728),
      (const uint4*)(ws + 90112), (const uint4*)(ws + 106496),
      b1w, b2w, b1t, b2t, out);
}